// Round 4
// baseline (541.312 us; speedup 1.0000x reference)
//
#include <hip/hip_runtime.h>
#include <math.h>

// N=8192 all-pairs wind-influence graph. Output: [edge_attr f32 N*N][mask01 f32 N*N]
//
// Round 4: hoist per-point trig to a one-shot table kernel.
//   Round 3's j-side sincos setup was recomputed by all 512 i-tile blocks per
//   column: 16.8M precise sincosf ~= 840M lane-ops, dominating VALU. Now a
//   precompute kernel writes tab[N][12] = {s,c,hs,hc,hsl,hcl,sl,cl,swr,cwr,ws10,0}
//   (393 KB, L2-resident) once; the main kernel loads it (float4) instead.
//   Table values are BIT-IDENTICAL to round 3's in-thread computation (same
//   sincosf on same inputs), pair math untouched -> numerics preserved.
// Early-out: a > ACUT  =>  dist > 175.6 km  =>  influence <= 1.5*exp(-1.756)
//   = 0.259 < 0.3  =>  both outputs provably 0; ~99.3% of pairs take this.
// Diagonal: slow path, j!=i in mask kills it.

#define NN 8192
#define TI 16      // i-rows per block
#define TJ 1024    // j-cols per block = 256 threads * 4
#define ACUT 1.9e-4f
#define TAB_FLOATS (NN * 12)

__global__ __launch_bounds__(256) void precomp_kernel(
    const float* __restrict__ pos,
    const float* __restrict__ wspd,
    const float* __restrict__ wdir,
    float* __restrict__ tab)           // (N,12)
{
    const int i = blockIdx.x * 256 + threadIdx.x;
    if (i >= NN) return;
    const float DEG2RAD = 0.017453292519943295f;
    float latr = pos[2 * i]     * DEG2RAD;
    float lonr = pos[2 * i + 1] * DEG2RAD;
    float wr   = wdir[i]        * DEG2RAD;
    float s, c, hs, hc, hsl, hcl, sl, cl, swr, cwr;
    sincosf(latr,        &s,   &c);
    sincosf(0.5f * latr, &hs,  &hc);
    sincosf(0.5f * lonr, &hsl, &hcl);
    sincosf(lonr,        &sl,  &cl);
    sincosf(wr,          &swr, &cwr);
    float* p = tab + i * 12;
    p[0] = s;   p[1] = c;   p[2]  = hs;  p[3]  = hc;
    p[4] = hsl; p[5] = hcl; p[6]  = sl;  p[7]  = cl;
    p[8] = swr; p[9] = cwr; p[10] = wspd[i] / 10.0f; p[11] = 0.0f;
}

__global__ __launch_bounds__(256) void dyn_graph_tab_kernel(
    const float* __restrict__ tab,     // (N,12)
    float* __restrict__ out)           // 2*N*N floats
{
    __shared__ __align__(16) float irow[TI * 12];

    const int tid   = threadIdx.x;
    const int i0    = blockIdx.y * TI;
    const int jbase = blockIdx.x * TJ + tid * 4;

    // ---- stage i-side table rows into LDS (48 float4) ----
    if (tid < TI * 3) {
        ((float4*)irow)[tid] = ((const float4*)tab)[i0 * 3 + tid];
    }

    // ---- j-side values: 2 float4 per j from the table ----
    float js[4], jc[4], jhs[4], jhc[4], jhsl[4], jhcl[4], jsl[4], jcl[4];
    #pragma unroll
    for (int k = 0; k < 4; ++k) {
        const float4* q = (const float4*)tab + (size_t)(jbase + k) * 3;
        float4 A = q[0], B = q[1];
        js[k]   = A.x; jc[k]   = A.y; jhs[k] = A.z; jhc[k] = A.w;
        jhsl[k] = B.x; jhcl[k] = B.y; jsl[k] = B.z; jcl[k] = B.w;
    }

    __syncthreads();

    #pragma unroll 1
    for (int r = 0; r < TI; ++r) {
        const float4* p4 = (const float4*)&irow[r * 12];
        float4 A = p4[0], B = p4[1], C = p4[2];
        const float is  = A.x, ic  = A.y, ihs = A.z, ihc = A.w;
        const float ihsl= B.x, ihcl= B.y, isl = B.z, icl = B.w;
        const float swr = C.x, cwr = C.y, ws10= C.z;
        const int i = i0 + r;

        float ev[4], mv[4];
        #pragma unroll
        for (int k = 0; k < 4; ++k) {
            float shlat = jhs[k] * ihc - jhc[k] * ihs;     // sin((lat2-lat1)/2)
            float shlon = jhsl[k] * ihcl - jhcl[k] * ihsl; // sin((lon2-lon1)/2)
            float cc = ic * jc[k];
            float a = shlat * shlat + cc * (shlon * shlon);

            ev[k] = 0.0f;
            mv[k] = 0.0f;

            if (a <= ACUT) {   // ~0.7% of pairs (plus diagonal) — unchanged slow path
                float ac = fminf(fmaxf(a, 1e-12f), 1.0f);
                float dist = 12742.0f * atan2f(sqrtf(ac), sqrtf(1.0f - ac));

                float sdlon = jsl[k] * icl - jcl[k] * isl;     // sin(dlon)
                float cdlon = jcl[k] * icl + jsl[k] * isl;     // cos(dlon)
                float x = sdlon * jc[k];
                float y = ic * js[k] - (is * jc[k]) * cdlon;

                float num = y * cwr + x * swr;                 // cos(atan2(x,y)-wr)*|v|
                float h2  = x * x + y * y;
                float align = num * rsqrtf(h2);

                float infl = align * ws10 * __expf(dist * -0.01f);
                bool m = (jbase + k != i) && (dist <= 300.0f) && (infl > 0.3f);
                ev[k] = m ? infl : 0.0f;
                mv[k] = m ? 1.0f : 0.0f;
            }
        }

        size_t idx = (size_t)i * NN + jbase;
        *(float4*)(out + idx) = make_float4(ev[0], ev[1], ev[2], ev[3]);
        *(float4*)(out + (size_t)NN * NN + idx) = make_float4(mv[0], mv[1], mv[2], mv[3]);
    }
}

// ---- round-3 fallback (used only if ws_size < table size) ----
__global__ __launch_bounds__(256) void dyn_graph_kernel_fb(
    const float* __restrict__ pos,
    const float* __restrict__ wspd,
    const float* __restrict__ wdir,
    float* __restrict__ out)
{
    __shared__ __align__(16) float irow[TI * 12];
    const int tid   = threadIdx.x;
    const int i0    = blockIdx.y * TI;
    const int jbase = blockIdx.x * TJ + tid * 4;
    const float DEG2RAD = 0.017453292519943295f;

    if (tid < TI) {
        int i = i0 + tid;
        float latr = pos[2 * i]     * DEG2RAD;
        float lonr = pos[2 * i + 1] * DEG2RAD;
        float wr   = wdir[i]        * DEG2RAD;
        float s, c, hs, hc, hsl, hcl, sl, cl, swr, cwr;
        sincosf(latr,        &s,   &c);
        sincosf(0.5f * latr, &hs,  &hc);
        sincosf(0.5f * lonr, &hsl, &hcl);
        sincosf(lonr,        &sl,  &cl);
        sincosf(wr,          &swr, &cwr);
        float* p = &irow[tid * 12];
        p[0] = s;   p[1] = c;   p[2]  = hs;  p[3]  = hc;
        p[4] = hsl; p[5] = hcl; p[6]  = sl;  p[7]  = cl;
        p[8] = swr; p[9] = cwr; p[10] = wspd[i] / 10.0f; p[11] = 0.0f;
    }

    float4 p01 = *(const float4*)(pos + 2 * jbase);
    float4 p23 = *(const float4*)(pos + 2 * jbase + 4);
    float jlat[4] = { p01.x, p01.z, p23.x, p23.z };
    float jlon[4] = { p01.y, p01.w, p23.y, p23.w };
    float js[4], jc[4], jhs[4], jhc[4], jhsl[4], jhcl[4], jsl[4], jcl[4];
    #pragma unroll
    for (int k = 0; k < 4; ++k) {
        float latr = jlat[k] * DEG2RAD;
        float lonr = jlon[k] * DEG2RAD;
        sincosf(latr,        &js[k],   &jc[k]);
        sincosf(0.5f * latr, &jhs[k],  &jhc[k]);
        sincosf(0.5f * lonr, &jhsl[k], &jhcl[k]);
        sincosf(lonr,        &jsl[k],  &jcl[k]);
    }
    __syncthreads();

    #pragma unroll 1
    for (int r = 0; r < TI; ++r) {
        const float4* p4 = (const float4*)&irow[r * 12];
        float4 A = p4[0], B = p4[1], C = p4[2];
        const float is  = A.x, ic  = A.y, ihs = A.z, ihc = A.w;
        const float ihsl= B.x, ihcl= B.y, isl = B.z, icl = B.w;
        const float swr = C.x, cwr = C.y, ws10= C.z;
        const int i = i0 + r;
        float ev[4], mv[4];
        #pragma unroll
        for (int k = 0; k < 4; ++k) {
            float shlat = jhs[k] * ihc - jhc[k] * ihs;
            float shlon = jhsl[k] * ihcl - jhcl[k] * ihsl;
            float cc = ic * jc[k];
            float a = shlat * shlat + cc * (shlon * shlon);
            ev[k] = 0.0f; mv[k] = 0.0f;
            if (a <= ACUT) {
                float ac = fminf(fmaxf(a, 1e-12f), 1.0f);
                float dist = 12742.0f * atan2f(sqrtf(ac), sqrtf(1.0f - ac));
                float sdlon = jsl[k] * icl - jcl[k] * isl;
                float cdlon = jcl[k] * icl + jsl[k] * isl;
                float x = sdlon * jc[k];
                float y = ic * js[k] - (is * jc[k]) * cdlon;
                float num = y * cwr + x * swr;
                float h2  = x * x + y * y;
                float align = num * rsqrtf(h2);
                float infl = align * ws10 * __expf(dist * -0.01f);
                bool m = (jbase + k != i) && (dist <= 300.0f) && (infl > 0.3f);
                ev[k] = m ? infl : 0.0f;
                mv[k] = m ? 1.0f : 0.0f;
            }
        }
        size_t idx = (size_t)i * NN + jbase;
        *(float4*)(out + idx) = make_float4(ev[0], ev[1], ev[2], ev[3]);
        *(float4*)(out + (size_t)NN * NN + idx) = make_float4(mv[0], mv[1], mv[2], mv[3]);
    }
}

extern "C" void kernel_launch(void* const* d_in, const int* in_sizes, int n_in,
                              void* d_out, int out_size, void* d_ws, size_t ws_size,
                              hipStream_t stream) {
    const float* pos  = (const float*)d_in[0];
    const float* wspd = (const float*)d_in[1];
    const float* wdir = (const float*)d_in[2];
    float* out = (float*)d_out;

    dim3 grid(NN / TJ, NN / TI);   // (8, 512)
    dim3 block(256);

    if (ws_size >= (size_t)TAB_FLOATS * sizeof(float)) {
        float* tab = (float*)d_ws;
        precomp_kernel<<<dim3(NN / 256), block, 0, stream>>>(pos, wspd, wdir, tab);
        dyn_graph_tab_kernel<<<grid, block, 0, stream>>>(tab, out);
    } else {
        dyn_graph_kernel_fb<<<grid, block, 0, stream>>>(pos, wspd, wdir, out);
    }
}

// Round 5
// 540.901 us; speedup vs baseline: 1.0008x; 1.0008x over previous
//
#include <hip/hip_runtime.h>
#include <math.h>

// N=8192 all-pairs wind-influence graph. Output: [edge_attr f32 N*N][mask01 f32 N*N]
//
// Round 5: fully branchless pair math.
//   atan2f(sqrt(a), sqrt(1-a)) == arcsin(sqrt(a)) on [0,1]. Mask-true pairs
//   have a <= 1.9e-4 (infl > 0.3 forces dist < 161 km), where the 2-term
//   series s + s^3/6 is accurate to 2.7e-9 relative — below f32 rounding.
//   For far pairs the series underestimates monotonically; since infl > 0.3
//   already implies dist << 300, no mask condition can flip. This removes the
//   divergent ~200-instr ocml atan2f path (35% of wave-k-iters entered it)
//   entirely: ~37 uniform VALU ops/pair, no branches in the hot loop.
//   Diagonal: x=y=0 -> num*rsqrt(0) = NaN -> all compares false -> (0,0),
//   and j!=i also excludes it, matching the reference eye-mask.
//   Per-point trig stays hoisted in a one-shot table kernel (L2-resident).

#define NN 8192
#define TI 16      // i-rows per block
#define TJ 1024    // j-cols per block = 256 threads * 4
#define TAB_FLOATS (NN * 12)

typedef float f4v __attribute__((ext_vector_type(4)));

__global__ __launch_bounds__(256) void precomp_kernel(
    const float* __restrict__ pos,
    const float* __restrict__ wspd,
    const float* __restrict__ wdir,
    float* __restrict__ tab)           // (N,12)
{
    const int i = blockIdx.x * 256 + threadIdx.x;
    if (i >= NN) return;
    const float DEG2RAD = 0.017453292519943295f;
    float latr = pos[2 * i]     * DEG2RAD;
    float lonr = pos[2 * i + 1] * DEG2RAD;
    float wr   = wdir[i]        * DEG2RAD;
    float s, c, hs, hc, hsl, hcl, sl, cl, swr, cwr;
    sincosf(latr,        &s,   &c);
    sincosf(0.5f * latr, &hs,  &hc);
    sincosf(0.5f * lonr, &hsl, &hcl);
    sincosf(lonr,        &sl,  &cl);
    sincosf(wr,          &swr, &cwr);
    float* p = tab + i * 12;
    p[0] = s;   p[1] = c;   p[2]  = hs;  p[3]  = hc;
    p[4] = hsl; p[5] = hcl; p[6]  = sl;  p[7]  = cl;
    p[8] = swr; p[9] = cwr; p[10] = wspd[i] / 10.0f; p[11] = 0.0f;
}

__device__ __forceinline__ void pair_body(
    float is, float ic, float ihs, float ihc,
    float ihsl, float ihcl, float isl, float icl,
    float swr, float cwr, float ws10,
    float js, float jc, float jhs, float jhc,
    float jhsl, float jhcl, float jsl, float jcl,
    bool offdiag, float* ev, float* mv)
{
    // haversine 'a' via cancellation-safe half-angle products
    float shlat = jhs * ihc - jhc * ihs;      // sin((lat2-lat1)/2)
    float shlon = jhsl * ihcl - jhcl * ihsl;  // sin((lon2-lon1)/2)
    float cc = ic * jc;
    float a = shlat * shlat + cc * (shlon * shlon);
    float ac = fminf(fmaxf(a, 1e-12f), 1.0f);

    // dist = 12742 * arcsin(s), 2-term series (exact-to-f32 for mask-true range)
    float s = sqrtf(ac);
    float s2 = s * s;
    float dist = fmaf(s * s2, 2123.6667f, s * 12742.0f);  // 12742*(s + s^3/6)

    // bearing vector
    float sdlon = jsl * icl - jcl * isl;      // sin(dlon)
    float cdlon = jcl * icl + jsl * isl;      // cos(dlon)
    float x = sdlon * jc;
    float y = ic * js - (is * jc) * cdlon;

    // alignment = cos(atan2(x,y) - wr)
    float num = y * cwr + x * swr;
    float h2  = x * x + y * y;
    float align = num * rsqrtf(h2);           // NaN on diagonal -> mask false

    float infl = align * ws10 * __expf(dist * -0.01f);
    bool m = offdiag && (dist <= 300.0f) && (infl > 0.3f);
    *ev = m ? infl : 0.0f;
    *mv = m ? 1.0f : 0.0f;
}

__global__ __launch_bounds__(256) void dyn_graph_tab_kernel(
    const float* __restrict__ tab,     // (N,12)
    float* __restrict__ out)           // 2*N*N floats
{
    __shared__ __align__(16) float irow[TI * 12];

    const int tid   = threadIdx.x;
    const int i0    = blockIdx.y * TI;
    const int jbase = blockIdx.x * TJ + tid * 4;

    if (tid < TI * 3) {
        ((float4*)irow)[tid] = ((const float4*)tab)[i0 * 3 + tid];
    }

    float js[4], jc[4], jhs[4], jhc[4], jhsl[4], jhcl[4], jsl[4], jcl[4];
    #pragma unroll
    for (int k = 0; k < 4; ++k) {
        const float4* q = (const float4*)tab + (size_t)(jbase + k) * 3;
        float4 A = q[0], B = q[1];
        js[k]   = A.x; jc[k]   = A.y; jhs[k] = A.z; jhc[k] = A.w;
        jhsl[k] = B.x; jhcl[k] = B.y; jsl[k] = B.z; jcl[k] = B.w;
    }

    __syncthreads();

    #pragma unroll 1
    for (int r = 0; r < TI; ++r) {
        const float4* p4 = (const float4*)&irow[r * 12];
        float4 A = p4[0], B = p4[1], C = p4[2];
        const int i = i0 + r;

        f4v ev, mv;
        #pragma unroll
        for (int k = 0; k < 4; ++k) {
            float e, m;
            pair_body(A.x, A.y, A.z, A.w, B.x, B.y, B.z, B.w, C.x, C.y, C.z,
                      js[k], jc[k], jhs[k], jhc[k], jhsl[k], jhcl[k], jsl[k], jcl[k],
                      (jbase + k) != i, &e, &m);
            ev[k] = e; mv[k] = m;
        }

        size_t idx = (size_t)i * NN + jbase;
        __builtin_nontemporal_store(ev, (f4v*)(out + idx));
        __builtin_nontemporal_store(mv, (f4v*)(out + (size_t)NN * NN + idx));
    }
}

// ---- fallback if ws too small: same branchless math, in-thread trig ----
__global__ __launch_bounds__(256) void dyn_graph_kernel_fb(
    const float* __restrict__ pos,
    const float* __restrict__ wspd,
    const float* __restrict__ wdir,
    float* __restrict__ out)
{
    __shared__ __align__(16) float irow[TI * 12];
    const int tid   = threadIdx.x;
    const int i0    = blockIdx.y * TI;
    const int jbase = blockIdx.x * TJ + tid * 4;
    const float DEG2RAD = 0.017453292519943295f;

    if (tid < TI) {
        int i = i0 + tid;
        float latr = pos[2 * i]     * DEG2RAD;
        float lonr = pos[2 * i + 1] * DEG2RAD;
        float wr   = wdir[i]        * DEG2RAD;
        float s, c, hs, hc, hsl, hcl, sl, cl, swr, cwr;
        sincosf(latr,        &s,   &c);
        sincosf(0.5f * latr, &hs,  &hc);
        sincosf(0.5f * lonr, &hsl, &hcl);
        sincosf(lonr,        &sl,  &cl);
        sincosf(wr,          &swr, &cwr);
        float* p = &irow[tid * 12];
        p[0] = s;   p[1] = c;   p[2]  = hs;  p[3]  = hc;
        p[4] = hsl; p[5] = hcl; p[6]  = sl;  p[7]  = cl;
        p[8] = swr; p[9] = cwr; p[10] = wspd[i] / 10.0f; p[11] = 0.0f;
    }

    float4 p01 = *(const float4*)(pos + 2 * jbase);
    float4 p23 = *(const float4*)(pos + 2 * jbase + 4);
    float jlat[4] = { p01.x, p01.z, p23.x, p23.z };
    float jlon[4] = { p01.y, p01.w, p23.y, p23.w };
    float js[4], jc[4], jhs[4], jhc[4], jhsl[4], jhcl[4], jsl[4], jcl[4];
    #pragma unroll
    for (int k = 0; k < 4; ++k) {
        float latr = jlat[k] * DEG2RAD;
        float lonr = jlon[k] * DEG2RAD;
        sincosf(latr,        &js[k],   &jc[k]);
        sincosf(0.5f * latr, &jhs[k],  &jhc[k]);
        sincosf(0.5f * lonr, &jhsl[k], &jhcl[k]);
        sincosf(lonr,        &jsl[k],  &jcl[k]);
    }
    __syncthreads();

    #pragma unroll 1
    for (int r = 0; r < TI; ++r) {
        const float4* p4 = (const float4*)&irow[r * 12];
        float4 A = p4[0], B = p4[1], C = p4[2];
        const int i = i0 + r;
        f4v ev, mv;
        #pragma unroll
        for (int k = 0; k < 4; ++k) {
            float e, m;
            pair_body(A.x, A.y, A.z, A.w, B.x, B.y, B.z, B.w, C.x, C.y, C.z,
                      js[k], jc[k], jhs[k], jhc[k], jhsl[k], jhcl[k], jsl[k], jcl[k],
                      (jbase + k) != i, &e, &m);
            ev[k] = e; mv[k] = m;
        }
        size_t idx = (size_t)i * NN + jbase;
        __builtin_nontemporal_store(ev, (f4v*)(out + idx));
        __builtin_nontemporal_store(mv, (f4v*)(out + (size_t)NN * NN + idx));
    }
}

extern "C" void kernel_launch(void* const* d_in, const int* in_sizes, int n_in,
                              void* d_out, int out_size, void* d_ws, size_t ws_size,
                              hipStream_t stream) {
    const float* pos  = (const float*)d_in[0];
    const float* wspd = (const float*)d_in[1];
    const float* wdir = (const float*)d_in[2];
    float* out = (float*)d_out;

    dim3 grid(NN / TJ, NN / TI);   // (8, 512)
    dim3 block(256);

    if (ws_size >= (size_t)TAB_FLOATS * sizeof(float)) {
        float* tab = (float*)d_ws;
        precomp_kernel<<<dim3(NN / 256), block, 0, stream>>>(pos, wspd, wdir, tab);
        dyn_graph_tab_kernel<<<grid, block, 0, stream>>>(tab, out);
    } else {
        dyn_graph_kernel_fb<<<grid, block, 0, stream>>>(pos, wspd, wdir, out);
    }
}